// Round 3
// baseline (292.508 us; speedup 1.0000x reference)
//
#include <hip/hip_runtime.h>
#include <hip/hip_bf16.h>

// HeteroLinear: out[b,n,o] = sum_i x[b,n,i] * W[t[n]][o][i] + bias[t[n]][o]
// B=16, N=16384, F_IN=F_OUT=128, NUM_TYPES=16, fp32 in/out.
//
// Round 3: (a) all bucketing fused into ONE single-block prep kernel
// (ballot-aggregated hist + prefix + scatter, plus padded block offsets);
// (b) main kernel 8 waves/block, exactly 1 node/wave (no serial loop),
// x prefetched before W staging, zero empty blocks, VGPR capped at 128.

#define NN 16384
#define FF 128
#define NT 16
#define NPB 8            // nodes per main block = waves per main block
#define NBLK (NN / NPB + NT)

typedef __bf16 bf16x8 __attribute__((ext_vector_type(8)));
typedef float  f32x4  __attribute__((ext_vector_type(4)));

// ws int layout: [0:16) cnt, [16:32) off, [32:49) blkoff[0..16], [64:64+NN) order

__global__ __launch_bounds__(1024) void hl_prep(const int* __restrict__ tv,
                                                int* __restrict__ ws) {
    __shared__ int wavehist[16][NT];
    __shared__ int soff[NT];
    __shared__ int cur[NT];
    const int tid  = threadIdx.x;
    const int wv   = tid >> 6;
    const int lane = tid & 63;

    int myt[16];
    int rc[NT];
#pragma unroll
    for (int i = 0; i < NT; ++i) rc[i] = 0;
#pragma unroll
    for (int i = 0; i < 16; ++i) {
        const int n = i * 1024 + tid;
        const int t = tv[n];
        myt[i] = t;
#pragma unroll
        for (int ty = 0; ty < NT; ++ty)
            rc[ty] += __popcll(__ballot(t == ty));
    }
    if (lane == 0) {
#pragma unroll
        for (int ty = 0; ty < NT; ++ty) wavehist[wv][ty] = rc[ty];
    }
    __syncthreads();
    if (tid < NT) {
        int s = 0;
        for (int w2 = 0; w2 < 16; ++w2) s += wavehist[w2][tid];
        ws[tid] = s;
        soff[tid] = s;      // temporarily cnt; fixed by thread 0 below
        cur[tid] = 0;
    }
    __syncthreads();
    if (tid == 0) {
        int acc = 0, bacc = 0;
        for (int t = 0; t < NT; ++t) {
            const int c = soff[t];
            soff[t] = acc;
            ws[16 + t] = acc;
            ws[32 + t] = bacc;
            acc  += c;
            bacc += (c + NPB - 1) / NPB;
        }
        ws[48] = bacc;      // blkoff[16] = total real blocks
    }
    __syncthreads();
#pragma unroll
    for (int i = 0; i < 16; ++i) {
        const int n = i * 1024 + tid;
        const int t = myt[i];
#pragma unroll
        for (int ty = 0; ty < NT; ++ty) {
            const unsigned long long m = __ballot(t == ty);
            const int c = __popcll(m);
            if (c) {
                int base = 0;
                if (lane == 0) base = atomicAdd(&cur[ty], c);
                base = __shfl(base, 0);
                if (t == ty) {
                    const int pos = base + __popcll(m & ((1ull << lane) - 1ull));
                    ws[64 + soff[ty] + pos] = n;
                }
            }
        }
    }
}

__global__ __launch_bounds__(512, 4) void hl_main(
    const float* __restrict__ x,      // [16][NN][128]
    const float* __restrict__ W,      // [16][128][128]
    const float* __restrict__ bias,   // [16][128]
    const int*   __restrict__ ws,
    float*       __restrict__ out)    // [16][NN][128]
{
    const int lane = threadIdx.x & 63;
    const int wv   = threadIdx.x >> 6;   // 0..7 = node slot in chunk

    // block -> (type, chunk) via padded block offsets
    const int probe = (lane < 17) ? ws[32 + lane] : 0x7fffffff;
    const unsigned long long m = __ballot(lane < 17 && (int)blockIdx.x >= probe);
    const int t = __popcll(m) - 1;
    if (t >= NT) return;

    const int cnt   = ws[t];
    const int off   = ws[16 + t];
    const int chunk = blockIdx.x - ws[32 + t];
    const int start = chunk * NPB;
    const int nn    = min(NPB, cnt - start);
    const bool valid = (wv < nn);
    const int n = ws[64 + off + start + (valid ? wv : 0)];

    const int lrow = lane & 15;   // A row (b) / B col (o) / D col (o)
    const int lgrp = lane >> 4;   // k-group of 8 / D row-group

    // prefetch this wave's x tile before W staging (latency overlaps staging)
    const float* xp = x + (size_t)lrow * ((size_t)NN * FF) + (size_t)n * FF + lgrp * 8;
    f32x4 xv[8];
#pragma unroll
    for (int kk = 0; kk < 4; ++kk) {
        xv[2 * kk]     = *(const f32x4*)(xp + kk * 32);
        xv[2 * kk + 1] = *(const f32x4*)(xp + kk * 32 + 4);
    }

    // stage W[t] as bf16 [o][k], 256B/row, XOR-swizzled 16B slots
    __shared__ __align__(16) unsigned char Wl[FF * 256];
    const float* Wt = W + t * (FF * FF);
#pragma unroll
    for (int ii = 0; ii < 4; ++ii) {
        const int idx = ii * 512 + threadIdx.x;
        const float* p = Wt + idx * 8;
        f32x4 a = *(const f32x4*)p;
        f32x4 b = *(const f32x4*)(p + 4);
        bf16x8 v;
#pragma unroll
        for (int j = 0; j < 4; ++j) { v[j] = (__bf16)a[j]; v[4 + j] = (__bf16)b[j]; }
        const int o  = idx >> 4;
        const int cb = (idx & 15) << 4;
        *(bf16x8*)(Wl + o * 256 + (cb ^ ((o & 7) << 4))) = v;
    }
    __syncthreads();

    // split x into hi/lo bf16
    bf16x8 ahi[4], alo[4];
#pragma unroll
    for (int kk = 0; kk < 4; ++kk) {
#pragma unroll
        for (int j = 0; j < 4; ++j) {
            const float f0 = xv[2 * kk][j], f1 = xv[2 * kk + 1][j];
            const __bf16 h0 = (__bf16)f0, h1 = (__bf16)f1;
            ahi[kk][j]     = h0;  alo[kk][j]     = (__bf16)(f0 - (float)h0);
            ahi[kk][4 + j] = h1;  alo[kk][4 + j] = (__bf16)(f1 - (float)h1);
        }
    }

    f32x4 acc[8];
#pragma unroll
    for (int ot = 0; ot < 8; ++ot) acc[ot] = (f32x4){0.f, 0.f, 0.f, 0.f};

#pragma unroll
    for (int kk = 0; kk < 4; ++kk) {
#pragma unroll
        for (int ot = 0; ot < 8; ++ot) {
            const int o  = ot * 16 + lrow;
            const int cb = (kk * 64 + lgrp * 16) ^ ((o & 7) << 4);
            const bf16x8 wf = *(const bf16x8*)(Wl + o * 256 + cb);
            acc[ot] = __builtin_amdgcn_mfma_f32_16x16x32_bf16(ahi[kk], wf, acc[ot], 0, 0, 0);
            acc[ot] = __builtin_amdgcn_mfma_f32_16x16x32_bf16(alo[kk], wf, acc[ot], 0, 0, 0);
        }
    }

    if (valid) {
#pragma unroll
        for (int ot = 0; ot < 8; ++ot) {
            const int o  = ot * 16 + lrow;
            const float bv = bias[t * FF + o];
#pragma unroll
            for (int r = 0; r < 4; ++r) {
                out[(size_t)(lgrp * 4 + r) * ((size_t)NN * FF) + (size_t)n * FF + o]
                    = acc[ot][r] + bv;
            }
        }
    }
}

extern "C" void kernel_launch(void* const* d_in, const int* in_sizes, int n_in,
                              void* d_out, int out_size, void* d_ws, size_t ws_size,
                              hipStream_t stream) {
    const float* x    = (const float*)d_in[0];
    const int*   tv   = (const int*)d_in[1];
    const float* W    = (const float*)d_in[2];
    const float* bias = (const float*)d_in[3];
    float*       out  = (float*)d_out;
    int*         wsI  = (int*)d_ws;

    hl_prep<<<1, 1024, 0, stream>>>(tv, wsI);
    hl_main<<<NBLK, 512, 0, stream>>>(x, W, bias, wsI, out);
}

// Round 4
// 69.458 us; speedup vs baseline: 4.2113x; 4.2113x over previous
//
#include <hip/hip_runtime.h>
#include <hip/hip_bf16.h>

// HeteroLinear: out[b,n,o] = sum_i x[b,n,i] * W[t[n]][o][i] + bias[t[n]][o]
// B=16, N=16384, F_IN=F_OUT=128, NUM_TYPES=16, fp32 in/out.
//
// Round 4: main kernel unchanged (measured ~47us, at the ~43us HBM floor).
// Prep rebuilt as a parallel deterministic 3-kernel pipeline (hist ->
// prefix -> scatter), no global atomics, ~64 blocks each. Round 3's
// single-block prep serialized 16K elements on one CU (245us).

#define NN 16384
#define FF 128
#define NT 16
#define NPB 8            // nodes per main block = waves per main block
#define NBLK (NN / NPB + NT)
#define PB 64            // prep blocks
#define WS_BH 16448      // ws offset of bh[t*PB + b] (after order array)

typedef __bf16 bf16x8 __attribute__((ext_vector_type(8)));
typedef float  f32x4  __attribute__((ext_vector_type(4)));

// ws int layout: [0:16) cnt, [16:32) off, [32:49) blkoff[0..16],
//                [64:64+NN) order, [WS_BH:WS_BH+NT*PB) per-block bases

__global__ __launch_bounds__(256) void hl_hist(const int* __restrict__ tv,
                                               int* __restrict__ ws) {
    __shared__ int wh[4][NT];
    const int tid = threadIdx.x, lane = tid & 63, wv = tid >> 6;
    const int t = tv[blockIdx.x * 256 + tid];
#pragma unroll
    for (int ty = 0; ty < NT; ++ty) {
        const unsigned long long m = __ballot(t == ty);
        if (lane == 0) wh[wv][ty] = __popcll(m);
    }
    __syncthreads();
    if (tid < NT)
        ws[WS_BH + tid * PB + blockIdx.x] = wh[0][tid] + wh[1][tid] + wh[2][tid] + wh[3][tid];
}

__global__ __launch_bounds__(1024) void hl_prefix(int* __restrict__ ws) {
    __shared__ int bh[NT * PB];
    __shared__ int scnt[NT];
    __shared__ int soff[NT];
    const int tid = threadIdx.x;
    bh[tid] = ws[WS_BH + tid];
    __syncthreads();
    if (tid < NT) {                       // prefix along blocks for type=tid
        int acc = 0;
        for (int b = 0; b < PB; ++b) { const int c = bh[tid * PB + b]; bh[tid * PB + b] = acc; acc += c; }
        scnt[tid] = acc;
        ws[tid] = acc;
    }
    __syncthreads();
    if (tid == 0) {
        int acc = 0, bacc = 0;
        for (int t = 0; t < NT; ++t) {
            soff[t] = acc;
            ws[16 + t] = acc;
            ws[32 + t] = bacc;
            acc  += scnt[t];
            bacc += (scnt[t] + NPB - 1) / NPB;
        }
        ws[48] = bacc;
    }
    __syncthreads();
    ws[WS_BH + tid] = bh[tid] + soff[tid >> 6];   // per-(type,block) global base
}

__global__ __launch_bounds__(256) void hl_scatter(const int* __restrict__ tv,
                                                  int* __restrict__ ws) {
    __shared__ int wh[4][NT];
    __shared__ int wbase[4][NT];
    const int tid = threadIdx.x, lane = tid & 63, wv = tid >> 6;
    const int n = blockIdx.x * 256 + tid;
    const int t = tv[n];
    int myrank = 0;
#pragma unroll
    for (int ty = 0; ty < NT; ++ty) {
        const unsigned long long m = __ballot(t == ty);
        if (lane == 0) wh[wv][ty] = __popcll(m);
        if (t == ty) myrank = __popcll(m & ((1ull << lane) - 1ull));
    }
    __syncthreads();
    if (tid < NT) {
        int base = ws[WS_BH + tid * PB + blockIdx.x];
        for (int w = 0; w < 4; ++w) { wbase[w][tid] = base; base += wh[w][tid]; }
    }
    __syncthreads();
    ws[64 + wbase[wv][t] + myrank] = n;
}

__global__ __launch_bounds__(512, 4) void hl_main(
    const float* __restrict__ x,      // [16][NN][128]
    const float* __restrict__ W,      // [16][128][128]
    const float* __restrict__ bias,   // [16][128]
    const int*   __restrict__ ws,
    float*       __restrict__ out)    // [16][NN][128]
{
    const int lane = threadIdx.x & 63;
    const int wv   = threadIdx.x >> 6;   // 0..7 = node slot in chunk

    // block -> (type, chunk) via padded block offsets
    const int probe = (lane < 17) ? ws[32 + lane] : 0x7fffffff;
    const unsigned long long m = __ballot(lane < 17 && (int)blockIdx.x >= probe);
    const int t = __popcll(m) - 1;
    if (t >= NT) return;

    const int cnt   = ws[t];
    const int off   = ws[16 + t];
    const int chunk = blockIdx.x - ws[32 + t];
    const int start = chunk * NPB;
    const int nn    = min(NPB, cnt - start);
    const bool valid = (wv < nn);
    const int n = ws[64 + off + start + (valid ? wv : 0)];

    const int lrow = lane & 15;   // A row (b) / B col (o) / D col (o)
    const int lgrp = lane >> 4;   // k-group of 8 / D row-group

    // prefetch this wave's x tile before W staging (latency overlaps staging)
    const float* xp = x + (size_t)lrow * ((size_t)NN * FF) + (size_t)n * FF + lgrp * 8;
    f32x4 xv[8];
#pragma unroll
    for (int kk = 0; kk < 4; ++kk) {
        xv[2 * kk]     = *(const f32x4*)(xp + kk * 32);
        xv[2 * kk + 1] = *(const f32x4*)(xp + kk * 32 + 4);
    }

    // stage W[t] as bf16 [o][k], 256B/row, XOR-swizzled 16B slots
    __shared__ __align__(16) unsigned char Wl[FF * 256];
    const float* Wt = W + t * (FF * FF);
#pragma unroll
    for (int ii = 0; ii < 4; ++ii) {
        const int idx = ii * 512 + threadIdx.x;
        const float* p = Wt + idx * 8;
        f32x4 a = *(const f32x4*)p;
        f32x4 b = *(const f32x4*)(p + 4);
        bf16x8 v;
#pragma unroll
        for (int j = 0; j < 4; ++j) { v[j] = (__bf16)a[j]; v[4 + j] = (__bf16)b[j]; }
        const int o  = idx >> 4;
        const int cb = (idx & 15) << 4;
        *(bf16x8*)(Wl + o * 256 + (cb ^ ((o & 7) << 4))) = v;
    }
    __syncthreads();

    // split x into hi/lo bf16
    bf16x8 ahi[4], alo[4];
#pragma unroll
    for (int kk = 0; kk < 4; ++kk) {
#pragma unroll
        for (int j = 0; j < 4; ++j) {
            const float f0 = xv[2 * kk][j], f1 = xv[2 * kk + 1][j];
            const __bf16 h0 = (__bf16)f0, h1 = (__bf16)f1;
            ahi[kk][j]     = h0;  alo[kk][j]     = (__bf16)(f0 - (float)h0);
            ahi[kk][4 + j] = h1;  alo[kk][4 + j] = (__bf16)(f1 - (float)h1);
        }
    }

    f32x4 acc[8];
#pragma unroll
    for (int ot = 0; ot < 8; ++ot) acc[ot] = (f32x4){0.f, 0.f, 0.f, 0.f};

#pragma unroll
    for (int kk = 0; kk < 4; ++kk) {
#pragma unroll
        for (int ot = 0; ot < 8; ++ot) {
            const int o  = ot * 16 + lrow;
            const int cb = (kk * 64 + lgrp * 16) ^ ((o & 7) << 4);
            const bf16x8 wf = *(const bf16x8*)(Wl + o * 256 + cb);
            acc[ot] = __builtin_amdgcn_mfma_f32_16x16x32_bf16(ahi[kk], wf, acc[ot], 0, 0, 0);
            acc[ot] = __builtin_amdgcn_mfma_f32_16x16x32_bf16(alo[kk], wf, acc[ot], 0, 0, 0);
        }
    }

    if (valid) {
#pragma unroll
        for (int ot = 0; ot < 8; ++ot) {
            const int o  = ot * 16 + lrow;
            const float bv = bias[t * FF + o];
#pragma unroll
            for (int r = 0; r < 4; ++r) {
                out[(size_t)(lgrp * 4 + r) * ((size_t)NN * FF) + (size_t)n * FF + o]
                    = acc[ot][r] + bv;
            }
        }
    }
}

extern "C" void kernel_launch(void* const* d_in, const int* in_sizes, int n_in,
                              void* d_out, int out_size, void* d_ws, size_t ws_size,
                              hipStream_t stream) {
    const float* x    = (const float*)d_in[0];
    const int*   tv   = (const int*)d_in[1];
    const float* W    = (const float*)d_in[2];
    const float* bias = (const float*)d_in[3];
    float*       out  = (float*)d_out;
    int*         wsI  = (int*)d_ws;

    hl_hist<<<PB, 256, 0, stream>>>(tv, wsI);
    hl_prefix<<<1, 1024, 0, stream>>>(wsI);
    hl_scatter<<<PB, 256, 0, stream>>>(tv, wsI);
    hl_main<<<NBLK, 512, 0, stream>>>(x, W, bias, wsI, out);
}